// Round 13
// baseline (161.146 us; speedup 1.0000x reference)
//
#include <hip/hip_runtime.h>
#include <hip/hip_bf16.h>
#include <hip/hip_fp16.h>

typedef int   i32x4 __attribute__((ext_vector_type(4)));
typedef float f32x4 __attribute__((ext_vector_type(4)));

// global -> LDS direct DMA, 16B per lane, linear LDS dest (base + lane*16)
#define GLD16(gp, lp)                                                   \
  __builtin_amdgcn_global_load_lds(                                     \
      (const __attribute__((address_space(1))) unsigned int*)(gp),      \
      (__attribute__((address_space(3))) unsigned int*)(lp), 16, 0, 0)

// ---------- helpers ----------

__device__ inline float f16round(float s) {   // s.astype(f16).astype(f32)
  return __half2float(__float2half(s));
}

__device__ inline float qclip(float x, float s, float qmax) {
  return fminf(fmaxf(rintf(x / s), -qmax), qmax);   // rintf = round-half-even (matches jnp.round)
}

__device__ inline float wave_absmax(float m) {
#pragma unroll
  for (int off = 32; off; off >>= 1) m = fmaxf(m, __shfl_xor(m, off));
  return m;
}

// ---------- fused input quant: wave-per-row, zero barriers, register-held ----------
// gw: [0,M) x-rows | [M,M+rank) v-rows | [M+rank,..) u-rows.
// x/v rows are read ONCE per launch -> NONTEMPORAL loads (no cache alloc on
// miss; still hits if resident).  Values held in registers (r11 lesson:
// re-read was not cache-hot).  u-rows: gathered values register-held; uw
// keeps normal loads (intra-row line reuse via gather).

__global__ __launch_bounds__(256) void quant_all_kernel(
    const float* __restrict__ x, const float* __restrict__ vw,
    const float* __restrict__ uw,
    const int* __restrict__ hi, const int* __restrict__ lo,
    int M, int r_high, int rank, int C,
    char* __restrict__ xq, float* __restrict__ xs,
    char* __restrict__ vq, float* __restrict__ vs,
    char* __restrict__ uq, float* __restrict__ ush, float* __restrict__ usl,
    unsigned* __restrict__ s2b) {
  int l  = threadIdx.x & 63;
  int gw = blockIdx.x * 4 + (threadIdx.x >> 6);
  if (gw < M + rank) {
    // ---- x-row or v-row: 4096 floats, single-pass, register-held ----
    int row; const f32x4* src; float qmax;
    if (gw < M) {
      row = gw;
      if (l == 0) { s2b[row] = 0u; s2b[M + row] = 0u; }  // zero for gemm1 atomics
      src = (const f32x4*)(x + (size_t)row * C);
      qmax = 127.f;
    } else {
      int vb = gw - M;
      int srow;
      if (vb < r_high) { srow = hi[vb]; qmax = 127.f; }
      else             { srow = lo[vb - r_high]; qmax = 7.f; }
      row = vb;
      src = (const f32x4*)(vw + (size_t)srow * C);
    }
    f32x4 v[16];
    float m = 0.f;
#pragma unroll
    for (int j = 0; j < 16; ++j) {
      v[j] = __builtin_nontemporal_load(&src[l + j * 64]);
      m = fmaxf(m, fmaxf(fmaxf(fabsf(v[j][0]), fabsf(v[j][1])),
                         fmaxf(fabsf(v[j][2]), fabsf(v[j][3]))));
    }
    m = wave_absmax(m);
    float s = fmaxf(m, 1e-8f) / qmax;
    char4* dst;
    if (gw < M) {
      if (l == 0) xs[row] = s;            // x_scale stays fp32
      dst = (char4*)(xq + (size_t)row * C);
    } else {
      if (l == 0) vs[row] = f16round(s);  // weight scale through f16
      dst = (char4*)(vq + (size_t)row * C);
    }
#pragma unroll
    for (int j = 0; j < 16; ++j) {
      char4 o;
      o.x = (char)qclip(v[j][0], s, qmax);
      o.y = (char)qclip(v[j][1], s, qmax);
      o.z = (char)qclip(v[j][2], s, qmax);
      o.w = (char)qclip(v[j][3], s, qmax);
      dst[l + j * 64] = o;
    }
  } else {
    // ---- u-row gather quant: values stay in registers ----
    int i = gw - M - rank;
    const float* urow = uw + (size_t)i * rank;
    float hv[4]; float mh = 0.f;
#pragma unroll
    for (int j = 0; j < 4; ++j) {         // r_high = 256 = 4*64
      hv[j] = urow[hi[l + j * 64]];
      mh = fmaxf(mh, fabsf(hv[j]));
    }
    mh = wave_absmax(mh);
    float sh = fmaxf(mh, 1e-8f) / 127.f;
    if (l == 0) ush[i] = f16round(sh);
#pragma unroll
    for (int j = 0; j < 4; ++j)
      uq[(size_t)i * rank + l + j * 64] = (char)qclip(hv[j], sh, 127.f);
    float lv[12]; float ml = 0.f;
#pragma unroll
    for (int j = 0; j < 12; ++j) {        // rank - r_high = 768 = 12*64
      lv[j] = urow[lo[l + j * 64]];
      ml = fmaxf(ml, fabsf(lv[j]));
    }
    ml = wave_absmax(ml);
    float sl = fmaxf(ml, 1e-8f) / 7.f;
    if (l == 0) usl[i] = f16round(sl);
#pragma unroll
    for (int j = 0; j < 12; ++j)
      uq[(size_t)i * rank + r_high + l + j * 64] = (char)qclip(lv[j], sl, 7.f);
  }
}

// ---------- re-quant of y1 (lean): scales precomputed by gemm1 atomics ----------
// y1 is dead after this read -> nontemporal load.

__global__ __launch_bounds__(256) void quant_y1_kernel(
    const f32x4* __restrict__ y1, char4* __restrict__ y1q,
    const unsigned* __restrict__ s2b, int M) {
  int total = M * 256;                    // rank/4 = 256 float4 per row
  for (int i = blockIdx.x * 256 + threadIdx.x; i < total;
       i += gridDim.x * 256) {
    int row = i >> 8, c4 = i & 255;
    float m = __uint_as_float(s2b[(c4 < 64 ? 0 : M) + row]);
    float s = fmaxf(m, 1e-8f) / 127.f;
    f32x4 v = __builtin_nontemporal_load(&y1[i]);
    char4 o;
    o.x = (char)qclip(v[0], s, 127.f);
    o.y = (char)qclip(v[1], s, 127.f);
    o.z = (char)qclip(v[2], s, 127.f);
    o.w = (char)qclip(v[3], s, 127.f);
    y1q[i] = o;
  }
}

// ---------- GEMM geometry (int8, best-known structure) ----------
// Block tile 64(M) x 128(N), BK = 128 i8 elements (128 BYTES per LDS row).
// 256 threads = 4 waves in 2x2; wave tile 32x64 = 2x4 frags of
// mfma_i32_16x16x64_i8.  Single-buffer 2-barrier K-loop.  Staging:
// global_load_lds width=16, linear LDS dest; XOR swizzle g=(l&7)^(row&7)
// pre-applied to the GLOBAL source address (rule #21).
// gemm2: NONTEMPORAL Out stores (r9 PMC: RFO fetch ~= Out size), occupancy 4.

#define BM 64
#define BN 128
#define BKT 128   // i8 elements per K-tile = bytes per LDS row

__global__ __launch_bounds__(256, 4) void gemm1_kernel(
    const char* __restrict__ A,   // xq: M x K i8
    const char* __restrict__ B,   // vq: N x K i8
    const float* __restrict__ xs, const float* __restrict__ ws,
    float* __restrict__ Y, unsigned* __restrict__ s2b,
    int M, int N, int K, int r_high) {
  __shared__ char smA[BM * BKT];   // 8 KB
  __shared__ char smB[BN * BKT];   // 16 KB
  int m0 = blockIdx.y * BM, n0 = blockIdx.x * BN;
  int tid = threadIdx.x, l = tid & 63, w = tid >> 6;
  int wr = w >> 1, wc = w & 1;

  int rb = w * 8 + (l >> 3);                // 0..31
  int g  = (l & 7) ^ (rb & 7);              // pre-swizzled 16B group
  const char* pA = A + (size_t)(m0 + rb) * K + g * 16;
  const char* pB = B + (size_t)(n0 + rb) * K + g * 16;
  char* ldsA = smA + w * 1024;              // + l*16 linear per wave
  char* ldsB = smB + w * 1024;

  i32x4 acc[2][4] = {};
  for (int k0 = 0; k0 < K; k0 += BKT) {
    __syncthreads();
#pragma unroll
    for (int i = 0; i < 2; ++i)
      GLD16(pA + (size_t)i * 32 * K + k0, ldsA + i * 4096);
#pragma unroll
    for (int i = 0; i < 4; ++i)
      GLD16(pB + (size_t)i * 32 * K + k0, ldsB + i * 4096);
    __syncthreads();
#pragma unroll
    for (int kk = 0; kk < 2; ++kk) {
      i32x4 af[2], bb[4];
      int lk = kk * 4 + (l >> 4);
#pragma unroll
      for (int f = 0; f < 2; ++f) {
        int ar = wr * 32 + f * 16 + (l & 15);
        af[f] = *(const i32x4*)(smA + ar * 128 + ((lk ^ (ar & 7)) << 4));
      }
#pragma unroll
      for (int f = 0; f < 4; ++f) {
        int br = wc * 64 + f * 16 + (l & 15);
        bb[f] = *(const i32x4*)(smB + br * 128 + ((lk ^ (br & 7)) << 4));
      }
#pragma unroll
      for (int i2 = 0; i2 < 2; ++i2)
#pragma unroll
        for (int j2 = 0; j2 < 4; ++j2)
          acc[i2][j2] = __builtin_amdgcn_mfma_i32_16x16x64_i8(
              af[i2], bb[j2], acc[i2][j2], 0, 0, 0);
    }
  }
  // epilogue: store scaled y1 + per-row partial absmax -> atomicMax (bits).
  float pm[2][4] = {};
#pragma unroll
  for (int i2 = 0; i2 < 2; ++i2)
#pragma unroll
    for (int j2 = 0; j2 < 4; ++j2) {
      int col = n0 + wc * 64 + j2 * 16 + (l & 15);
      float cs = ws[col];
#pragma unroll
      for (int r = 0; r < 4; ++r) {
        int row = m0 + wr * 32 + i2 * 16 + (l >> 4) * 4 + r;
        float v = (float)acc[i2][j2][r] * xs[row] * cs;
        Y[(size_t)row * N + col] = v;      // y1 is re-read -> keep cached
        pm[i2][r] = fmaxf(pm[i2][r], fabsf(v));
      }
    }
#pragma unroll
  for (int i2 = 0; i2 < 2; ++i2)
#pragma unroll
    for (int r = 0; r < 4; ++r) {
#pragma unroll
      for (int off = 1; off < 16; off <<= 1)
        pm[i2][r] = fmaxf(pm[i2][r], __shfl_xor(pm[i2][r], off));
    }
  if ((l & 15) == 0) {
    unsigned* dst = s2b + (n0 < r_high ? 0 : M);   // high cols -> [0,M)
#pragma unroll
    for (int i2 = 0; i2 < 2; ++i2)
#pragma unroll
      for (int r = 0; r < 4; ++r) {
        int row = m0 + wr * 32 + i2 * 16 + (l >> 4) * 4 + r;
        atomicMax(&dst[row], __float_as_uint(pm[i2][r]));
      }
  }
}

__global__ __launch_bounds__(256, 4) void gemm2_kernel(
    const char* __restrict__ A,   // y1q: M x K i8
    const char* __restrict__ B,   // uq:  N x K i8
    const unsigned* __restrict__ s2b,
    const float* __restrict__ ush, const float* __restrict__ usl,
    const float* __restrict__ bias,
    float* __restrict__ Out, int M, int N, int K, int r_high) {
  __shared__ char smA[BM * BKT];
  __shared__ char smB[BN * BKT];
  int m0 = blockIdx.y * BM, n0 = blockIdx.x * BN;
  int tid = threadIdx.x, l = tid & 63, w = tid >> 6;
  int wr = w >> 1, wc = w & 1;

  int rb = w * 8 + (l >> 3);
  int g  = (l & 7) ^ (rb & 7);
  const char* pA = A + (size_t)(m0 + rb) * K + g * 16;
  const char* pB = B + (size_t)(n0 + rb) * K + g * 16;
  char* ldsA = smA + w * 1024;
  char* ldsB = smB + w * 1024;

  i32x4 acch[2][4] = {};
  i32x4 accl[2][4] = {};

  auto ktile = [&](int k0, i32x4(&acc)[2][4]) {
    __syncthreads();
#pragma unroll
    for (int i = 0; i < 2; ++i)
      GLD16(pA + (size_t)i * 32 * K + k0, ldsA + i * 4096);
#pragma unroll
    for (int i = 0; i < 4; ++i)
      GLD16(pB + (size_t)i * 32 * K + k0, ldsB + i * 4096);
    __syncthreads();
#pragma unroll
    for (int kk = 0; kk < 2; ++kk) {
      i32x4 af[2], bb[4];
      int lk = kk * 4 + (l >> 4);
#pragma unroll
      for (int f = 0; f < 2; ++f) {
        int ar = wr * 32 + f * 16 + (l & 15);
        af[f] = *(const i32x4*)(smA + ar * 128 + ((lk ^ (ar & 7)) << 4));
      }
#pragma unroll
      for (int f = 0; f < 4; ++f) {
        int br = wc * 64 + f * 16 + (l & 15);
        bb[f] = *(const i32x4*)(smB + br * 128 + ((lk ^ (br & 7)) << 4));
      }
#pragma unroll
      for (int i2 = 0; i2 < 2; ++i2)
#pragma unroll
        for (int j2 = 0; j2 < 4; ++j2)
          acc[i2][j2] = __builtin_amdgcn_mfma_i32_16x16x64_i8(
              af[i2], bb[j2], acc[i2][j2], 0, 0, 0);
    }
  };

  for (int k0 = 0; k0 < r_high; k0 += BKT) ktile(k0, acch);   // high
  for (int k0 = r_high; k0 < K; k0 += BKT) ktile(k0, accl);   // low

  // per-thread row scales from the atomic absmax bits (8 distinct rows)
  float sh_[2][4], sl_[2][4];
#pragma unroll
  for (int i2 = 0; i2 < 2; ++i2)
#pragma unroll
    for (int r = 0; r < 4; ++r) {
      int row = m0 + wr * 32 + i2 * 16 + (l >> 4) * 4 + r;
      sh_[i2][r] = fmaxf(__uint_as_float(s2b[row]), 1e-8f) / 127.f;
      sl_[i2][r] = fmaxf(__uint_as_float(s2b[M + row]), 1e-8f) / 127.f;
    }

#pragma unroll
  for (int i2 = 0; i2 < 2; ++i2)
#pragma unroll
    for (int j2 = 0; j2 < 4; ++j2) {
      int col = n0 + wc * 64 + j2 * 16 + (l & 15);
      float uh = ush[col], ul = usl[col];
      float bc = f16round(bias[col]);
#pragma unroll
      for (int r = 0; r < 4; ++r) {
        int row = m0 + wr * 32 + i2 * 16 + (l >> 4) * 4 + r;
        float v = (float)acch[i2][j2][r] * (sh_[i2][r] * uh) +
                  (float)accl[i2][j2][r] * (sl_[i2][r] * ul) + bc;
        // Out is never re-read: nontemporal store avoids RFO fetch.
        __builtin_nontemporal_store(v, &Out[(size_t)row * N + col]);
      }
    }
}

// ---------- launch ----------

extern "C" void kernel_launch(void* const* d_in, const int* in_sizes, int n_in,
                              void* d_out, int out_size, void* d_ws, size_t ws_size,
                              hipStream_t stream) {
  const float* x    = (const float*)d_in[0];
  const float* uw   = (const float*)d_in[1];
  const float* vw   = (const float*)d_in[2];
  const float* bias = (const float*)d_in[3];
  const int*   hi   = (const int*)d_in[4];
  const int*   lo   = (const int*)d_in[5];

  const int in_f = 4096, out_f = 4096;
  const int rank   = in_sizes[1] / out_f;     // 1024
  const int r_high = in_sizes[4];             // 256
  const int M      = in_sizes[0] / in_f;      // 8192

  char* p = (char*)d_ws;
  auto take = [&](size_t bytes) {
    char* r = p;
    p += (bytes + 255) & ~(size_t)255;
    return r;
  };
  char*     xq  = take((size_t)M * in_f);
  float*    xs  = (float*)take((size_t)M * 4);
  char*     vq  = take((size_t)rank * in_f);
  float*    vs  = (float*)take((size_t)rank * 4);
  char*     uq  = take((size_t)out_f * rank);
  float*    ush = (float*)take((size_t)out_f * 4);
  float*    usl = (float*)take((size_t)out_f * 4);
  float*    y1  = (float*)take((size_t)M * rank * 4);
  char*     y1q = take((size_t)M * rank);
  unsigned* s2b = (unsigned*)take((size_t)2 * M * 4);

  quant_all_kernel<<<(M + rank + out_f) / 4, 256, 0, stream>>>(
      x, vw, uw, hi, lo, M, r_high, rank, in_f,
      xq, xs, vq, vs, uq, ush, usl, s2b);
  gemm1_kernel<<<dim3(rank / BN, M / BM), 256, 0, stream>>>(
      xq, vq, xs, vs, y1, s2b, M, rank, in_f, r_high);
  quant_y1_kernel<<<4096, 256, 0, stream>>>(
      (const f32x4*)y1, (char4*)y1q, s2b, M);
  gemm2_kernel<<<dim3(out_f / BN, M / BM), 256, 0, stream>>>(
      y1q, uq, s2b, ush, usl, bias, (float*)d_out, M, out_f, rank, r_high);
}

// Round 14
// 159.934 us; speedup vs baseline: 1.0076x; 1.0076x over previous
//
#include <hip/hip_runtime.h>
#include <hip/hip_bf16.h>
#include <hip/hip_fp16.h>

typedef int   i32x4 __attribute__((ext_vector_type(4)));
typedef float f32x4 __attribute__((ext_vector_type(4)));

// global -> LDS direct DMA, 16B per lane, linear LDS dest (base + lane*16)
#define GLD16(gp, lp)                                                   \
  __builtin_amdgcn_global_load_lds(                                     \
      (const __attribute__((address_space(1))) unsigned int*)(gp),      \
      (__attribute__((address_space(3))) unsigned int*)(lp), 16, 0, 0)

// ---------- helpers ----------

__device__ inline float f16round(float s) {   // s.astype(f16).astype(f32)
  return __half2float(__float2half(s));
}

__device__ inline float qclip(float x, float s, float qmax) {
  return fminf(fmaxf(rintf(x / s), -qmax), qmax);   // rintf = round-half-even (matches jnp.round)
}

__device__ inline float wave_absmax(float m) {
#pragma unroll
  for (int off = 32; off; off >>= 1) m = fmaxf(m, __shfl_xor(m, off));
  return m;
}

// ---------- quant of x-rows and v-rows (gemm1's inputs ONLY) ----------
// u-quant moved to the post-gemm1 launch: it is needed only by gemm2, and
// serializing its latency-bound gather ahead of gemm1 cost critical-path time.
// Wave-per-row, register-held (r12: clean compulsory FETCH), no barriers.

__global__ __launch_bounds__(256) void quant_xv_kernel(
    const float* __restrict__ x, const float* __restrict__ vw,
    const int* __restrict__ hi, const int* __restrict__ lo,
    int M, int r_high, int C,
    char* __restrict__ xq, float* __restrict__ xs,
    char* __restrict__ vq, float* __restrict__ vs,
    unsigned* __restrict__ s2b) {
  int l  = threadIdx.x & 63;
  int gw = blockIdx.x * 4 + (threadIdx.x >> 6);
  int row; const f32x4* src; float qmax;
  if (gw < M) {
    row = gw;
    if (l == 0) { s2b[row] = 0u; s2b[M + row] = 0u; }  // zero for gemm1 atomics
    src = (const f32x4*)(x + (size_t)row * C);
    qmax = 127.f;
  } else {
    int vb = gw - M;
    int srow;
    if (vb < r_high) { srow = hi[vb]; qmax = 127.f; }
    else             { srow = lo[vb - r_high]; qmax = 7.f; }
    row = vb;
    src = (const f32x4*)(vw + (size_t)srow * C);
  }
  f32x4 v[16];
  float m = 0.f;
#pragma unroll
  for (int j = 0; j < 16; ++j) {
    v[j] = src[l + j * 64];
    m = fmaxf(m, fmaxf(fmaxf(fabsf(v[j][0]), fabsf(v[j][1])),
                       fmaxf(fabsf(v[j][2]), fabsf(v[j][3]))));
  }
  m = wave_absmax(m);
  float s = fmaxf(m, 1e-8f) / qmax;
  char4* dst;
  if (gw < M) {
    if (l == 0) xs[row] = s;            // x_scale stays fp32
    dst = (char4*)(xq + (size_t)row * C);
  } else {
    if (l == 0) vs[row] = f16round(s);  // weight scale through f16
    dst = (char4*)(vq + (size_t)row * C);
  }
#pragma unroll
  for (int j = 0; j < 16; ++j) {
    char4 o;
    o.x = (char)qclip(v[j][0], s, qmax);
    o.y = (char)qclip(v[j][1], s, qmax);
    o.z = (char)qclip(v[j][2], s, qmax);
    o.w = (char)qclip(v[j][3], s, qmax);
    dst[l + j * 64] = o;
  }
}

// ---------- fused post-gemm1 quant: u-rows + y1 requant in ONE launch ----------
// blocks [0, nub):  u-row gather quant, wave-per-row (latency-bound gather)
// blocks [nub, ..): y1 requant grid-stride (BW-bound stream) — complementary
// bound-types co-schedule.  y1 scales precomputed by gemm1's atomics (s2b).

__global__ __launch_bounds__(256) void quant_y1_u_kernel(
    const f32x4* __restrict__ y1, char4* __restrict__ y1q,
    const unsigned* __restrict__ s2b, int M,
    const float* __restrict__ uw, const int* __restrict__ hi,
    const int* __restrict__ lo, int r_high, int rank,
    char* __restrict__ uq, float* __restrict__ ush, float* __restrict__ usl,
    int nub) {
  if ((int)blockIdx.x < nub) {
    int l = threadIdx.x & 63;
    int i = blockIdx.x * 4 + (threadIdx.x >> 6);   // u-row, < out_f
    const float* urow = uw + (size_t)i * rank;
    float hv[4]; float mh = 0.f;
#pragma unroll
    for (int j = 0; j < 4; ++j) {         // r_high = 256 = 4*64
      hv[j] = urow[hi[l + j * 64]];
      mh = fmaxf(mh, fabsf(hv[j]));
    }
    mh = wave_absmax(mh);
    float sh = fmaxf(mh, 1e-8f) / 127.f;
    if (l == 0) ush[i] = f16round(sh);
#pragma unroll
    for (int j = 0; j < 4; ++j)
      uq[(size_t)i * rank + l + j * 64] = (char)qclip(hv[j], sh, 127.f);
    float lv[12]; float ml = 0.f;
#pragma unroll
    for (int j = 0; j < 12; ++j) {        // rank - r_high = 768 = 12*64
      lv[j] = urow[lo[l + j * 64]];
      ml = fmaxf(ml, fabsf(lv[j]));
    }
    ml = wave_absmax(ml);
    float sl = fmaxf(ml, 1e-8f) / 7.f;
    if (l == 0) usl[i] = f16round(sl);
#pragma unroll
    for (int j = 0; j < 12; ++j)
      uq[(size_t)i * rank + r_high + l + j * 64] = (char)qclip(lv[j], sl, 7.f);
  } else {
    int nb = gridDim.x - nub;
    int total = M * 256;                  // rank/4 = 256 float4 per row
    for (int i = (blockIdx.x - nub) * 256 + threadIdx.x; i < total;
         i += nb * 256) {
      int row = i >> 8, c4 = i & 255;
      float m = __uint_as_float(s2b[(c4 < 64 ? 0 : M) + row]);
      float s = fmaxf(m, 1e-8f) / 127.f;
      f32x4 v = y1[i];
      char4 o;
      o.x = (char)qclip(v[0], s, 127.f);
      o.y = (char)qclip(v[1], s, 127.f);
      o.z = (char)qclip(v[2], s, 127.f);
      o.w = (char)qclip(v[3], s, 127.f);
      y1q[i] = o;
    }
  }
}

// ---------- GEMM geometry (int8, best-known r10 structure) ----------
// Block tile 64(M) x 128(N), BK = 128 i8 elements (128 BYTES per LDS row).
// 256 threads = 4 waves in 2x2; wave tile 32x64 = 2x4 frags of
// mfma_i32_16x16x64_i8.  Single-buffer 2-barrier K-loop.  Staging:
// global_load_lds width=16, linear LDS dest; XOR swizzle g=(l&7)^(row&7)
// pre-applied to the GLOBAL source address (rule #21).
// gemm2: NONTEMPORAL Out stores (r9 PMC: RFO fetch ~= Out size), occupancy 4.

#define BM 64
#define BN 128
#define BKT 128   // i8 elements per K-tile = bytes per LDS row

__global__ __launch_bounds__(256, 4) void gemm1_kernel(
    const char* __restrict__ A,   // xq: M x K i8
    const char* __restrict__ B,   // vq: N x K i8
    const float* __restrict__ xs, const float* __restrict__ ws,
    float* __restrict__ Y, unsigned* __restrict__ s2b,
    int M, int N, int K, int r_high) {
  __shared__ char smA[BM * BKT];   // 8 KB
  __shared__ char smB[BN * BKT];   // 16 KB
  int m0 = blockIdx.y * BM, n0 = blockIdx.x * BN;
  int tid = threadIdx.x, l = tid & 63, w = tid >> 6;
  int wr = w >> 1, wc = w & 1;

  int rb = w * 8 + (l >> 3);                // 0..31
  int g  = (l & 7) ^ (rb & 7);              // pre-swizzled 16B group
  const char* pA = A + (size_t)(m0 + rb) * K + g * 16;
  const char* pB = B + (size_t)(n0 + rb) * K + g * 16;
  char* ldsA = smA + w * 1024;              // + l*16 linear per wave
  char* ldsB = smB + w * 1024;

  i32x4 acc[2][4] = {};
  for (int k0 = 0; k0 < K; k0 += BKT) {
    __syncthreads();
#pragma unroll
    for (int i = 0; i < 2; ++i)
      GLD16(pA + (size_t)i * 32 * K + k0, ldsA + i * 4096);
#pragma unroll
    for (int i = 0; i < 4; ++i)
      GLD16(pB + (size_t)i * 32 * K + k0, ldsB + i * 4096);
    __syncthreads();
#pragma unroll
    for (int kk = 0; kk < 2; ++kk) {
      i32x4 af[2], bb[4];
      int lk = kk * 4 + (l >> 4);
#pragma unroll
      for (int f = 0; f < 2; ++f) {
        int ar = wr * 32 + f * 16 + (l & 15);
        af[f] = *(const i32x4*)(smA + ar * 128 + ((lk ^ (ar & 7)) << 4));
      }
#pragma unroll
      for (int f = 0; f < 4; ++f) {
        int br = wc * 64 + f * 16 + (l & 15);
        bb[f] = *(const i32x4*)(smB + br * 128 + ((lk ^ (br & 7)) << 4));
      }
#pragma unroll
      for (int i2 = 0; i2 < 2; ++i2)
#pragma unroll
        for (int j2 = 0; j2 < 4; ++j2)
          acc[i2][j2] = __builtin_amdgcn_mfma_i32_16x16x64_i8(
              af[i2], bb[j2], acc[i2][j2], 0, 0, 0);
    }
  }
  // epilogue: store scaled y1 + per-row partial absmax -> atomicMax (bits).
  float pm[2][4] = {};
#pragma unroll
  for (int i2 = 0; i2 < 2; ++i2)
#pragma unroll
    for (int j2 = 0; j2 < 4; ++j2) {
      int col = n0 + wc * 64 + j2 * 16 + (l & 15);
      float cs = ws[col];
#pragma unroll
      for (int r = 0; r < 4; ++r) {
        int row = m0 + wr * 32 + i2 * 16 + (l >> 4) * 4 + r;
        float v = (float)acc[i2][j2][r] * xs[row] * cs;
        Y[(size_t)row * N + col] = v;      // y1 is re-read -> keep cached
        pm[i2][r] = fmaxf(pm[i2][r], fabsf(v));
      }
    }
#pragma unroll
  for (int i2 = 0; i2 < 2; ++i2)
#pragma unroll
    for (int r = 0; r < 4; ++r) {
#pragma unroll
      for (int off = 1; off < 16; off <<= 1)
        pm[i2][r] = fmaxf(pm[i2][r], __shfl_xor(pm[i2][r], off));
    }
  if ((l & 15) == 0) {
    unsigned* dst = s2b + (n0 < r_high ? 0 : M);   // high cols -> [0,M)
#pragma unroll
    for (int i2 = 0; i2 < 2; ++i2)
#pragma unroll
      for (int r = 0; r < 4; ++r) {
        int row = m0 + wr * 32 + i2 * 16 + (l >> 4) * 4 + r;
        atomicMax(&dst[row], __float_as_uint(pm[i2][r]));
      }
  }
}

__global__ __launch_bounds__(256, 4) void gemm2_kernel(
    const char* __restrict__ A,   // y1q: M x K i8
    const char* __restrict__ B,   // uq:  N x K i8
    const unsigned* __restrict__ s2b,
    const float* __restrict__ ush, const float* __restrict__ usl,
    const float* __restrict__ bias,
    float* __restrict__ Out, int M, int N, int K, int r_high) {
  __shared__ char smA[BM * BKT];
  __shared__ char smB[BN * BKT];
  int m0 = blockIdx.y * BM, n0 = blockIdx.x * BN;
  int tid = threadIdx.x, l = tid & 63, w = tid >> 6;
  int wr = w >> 1, wc = w & 1;

  int rb = w * 8 + (l >> 3);
  int g  = (l & 7) ^ (rb & 7);
  const char* pA = A + (size_t)(m0 + rb) * K + g * 16;
  const char* pB = B + (size_t)(n0 + rb) * K + g * 16;
  char* ldsA = smA + w * 1024;
  char* ldsB = smB + w * 1024;

  i32x4 acch[2][4] = {};
  i32x4 accl[2][4] = {};

  auto ktile = [&](int k0, i32x4(&acc)[2][4]) {
    __syncthreads();
#pragma unroll
    for (int i = 0; i < 2; ++i)
      GLD16(pA + (size_t)i * 32 * K + k0, ldsA + i * 4096);
#pragma unroll
    for (int i = 0; i < 4; ++i)
      GLD16(pB + (size_t)i * 32 * K + k0, ldsB + i * 4096);
    __syncthreads();
#pragma unroll
    for (int kk = 0; kk < 2; ++kk) {
      i32x4 af[2], bb[4];
      int lk = kk * 4 + (l >> 4);
#pragma unroll
      for (int f = 0; f < 2; ++f) {
        int ar = wr * 32 + f * 16 + (l & 15);
        af[f] = *(const i32x4*)(smA + ar * 128 + ((lk ^ (ar & 7)) << 4));
      }
#pragma unroll
      for (int f = 0; f < 4; ++f) {
        int br = wc * 64 + f * 16 + (l & 15);
        bb[f] = *(const i32x4*)(smB + br * 128 + ((lk ^ (br & 7)) << 4));
      }
#pragma unroll
      for (int i2 = 0; i2 < 2; ++i2)
#pragma unroll
        for (int j2 = 0; j2 < 4; ++j2)
          acc[i2][j2] = __builtin_amdgcn_mfma_i32_16x16x64_i8(
              af[i2], bb[j2], acc[i2][j2], 0, 0, 0);
    }
  };

  for (int k0 = 0; k0 < r_high; k0 += BKT) ktile(k0, acch);   // high
  for (int k0 = r_high; k0 < K; k0 += BKT) ktile(k0, accl);   // low

  // per-thread row scales from the atomic absmax bits (8 distinct rows)
  float sh_[2][4], sl_[2][4];
#pragma unroll
  for (int i2 = 0; i2 < 2; ++i2)
#pragma unroll
    for (int r = 0; r < 4; ++r) {
      int row = m0 + wr * 32 + i2 * 16 + (l >> 4) * 4 + r;
      sh_[i2][r] = fmaxf(__uint_as_float(s2b[row]), 1e-8f) / 127.f;
      sl_[i2][r] = fmaxf(__uint_as_float(s2b[M + row]), 1e-8f) / 127.f;
    }

#pragma unroll
  for (int i2 = 0; i2 < 2; ++i2)
#pragma unroll
    for (int j2 = 0; j2 < 4; ++j2) {
      int col = n0 + wc * 64 + j2 * 16 + (l & 15);
      float uh = ush[col], ul = usl[col];
      float bc = f16round(bias[col]);
#pragma unroll
      for (int r = 0; r < 4; ++r) {
        int row = m0 + wr * 32 + i2 * 16 + (l >> 4) * 4 + r;
        float v = (float)acch[i2][j2][r] * (sh_[i2][r] * uh) +
                  (float)accl[i2][j2][r] * (sl_[i2][r] * ul) + bc;
        // Out is never re-read: nontemporal store avoids RFO fetch.
        __builtin_nontemporal_store(v, &Out[(size_t)row * N + col]);
      }
    }
}

// ---------- launch ----------

extern "C" void kernel_launch(void* const* d_in, const int* in_sizes, int n_in,
                              void* d_out, int out_size, void* d_ws, size_t ws_size,
                              hipStream_t stream) {
  const float* x    = (const float*)d_in[0];
  const float* uw   = (const float*)d_in[1];
  const float* vw   = (const float*)d_in[2];
  const float* bias = (const float*)d_in[3];
  const int*   hi   = (const int*)d_in[4];
  const int*   lo   = (const int*)d_in[5];

  const int in_f = 4096, out_f = 4096;
  const int rank   = in_sizes[1] / out_f;     // 1024
  const int r_high = in_sizes[4];             // 256
  const int M      = in_sizes[0] / in_f;      // 8192

  char* p = (char*)d_ws;
  auto take = [&](size_t bytes) {
    char* r = p;
    p += (bytes + 255) & ~(size_t)255;
    return r;
  };
  char*     xq  = take((size_t)M * in_f);
  float*    xs  = (float*)take((size_t)M * 4);
  char*     vq  = take((size_t)rank * in_f);
  float*    vs  = (float*)take((size_t)rank * 4);
  char*     uq  = take((size_t)out_f * rank);
  float*    ush = (float*)take((size_t)out_f * 4);
  float*    usl = (float*)take((size_t)out_f * 4);
  float*    y1  = (float*)take((size_t)M * rank * 4);
  char*     y1q = take((size_t)M * rank);
  unsigned* s2b = (unsigned*)take((size_t)2 * M * 4);

  // 1) quantize gemm1's inputs only (x rows + gathered v rows)
  quant_xv_kernel<<<(M + rank) / 4, 256, 0, stream>>>(
      x, vw, hi, lo, M, r_high, in_f, xq, xs, vq, vs, s2b);
  // 2) gemm1 (computes y1 + per-row split absmax via atomics)
  gemm1_kernel<<<dim3(rank / BN, M / BM), 256, 0, stream>>>(
      xq, vq, xs, vs, y1, s2b, M, rank, in_f, r_high);
  // 3) u-quant (gather, latency-bound) + y1 requant (stream, BW-bound) fused
  quant_y1_u_kernel<<<out_f / 4 + 2048, 256, 0, stream>>>(
      (const f32x4*)y1, (char4*)y1q, s2b, M,
      uw, hi, lo, r_high, rank, uq, ush, usl, out_f / 4);
  // 4) gemm2
  gemm2_kernel<<<dim3(out_f / BN, M / BM), 256, 0, stream>>>(
      y1q, uq, s2b, ush, usl, bias, (float*)d_out, M, out_f, rank, r_high);
}

// Round 15
// 155.758 us; speedup vs baseline: 1.0346x; 1.0268x over previous
//
#include <hip/hip_runtime.h>
#include <hip/hip_bf16.h>
#include <hip/hip_fp16.h>

typedef int   i32x4 __attribute__((ext_vector_type(4)));
typedef float f32x4 __attribute__((ext_vector_type(4)));

// global -> LDS direct DMA, 16B per lane, linear LDS dest (base + lane*16)
#define GLD16(gp, lp)                                                   \
  __builtin_amdgcn_global_load_lds(                                     \
      (const __attribute__((address_space(1))) unsigned int*)(gp),      \
      (__attribute__((address_space(3))) unsigned int*)(lp), 16, 0, 0)

// ---------- helpers ----------

__device__ inline float blk_absmax(float v, float* red) {
#pragma unroll
  for (int off = 32; off; off >>= 1) v = fmaxf(v, __shfl_xor(v, off));
  __syncthreads();                       // protect red[] reuse across calls
  if ((threadIdx.x & 63) == 0) red[threadIdx.x >> 6] = v;
  __syncthreads();
  return fmaxf(fmaxf(red[0], red[1]), fmaxf(red[2], red[3]));
}

__device__ inline float f16round(float s) {   // s.astype(f16).astype(f32)
  return __half2float(__float2half(s));
}

__device__ inline float qclip(float x, float s, float qmax) {
  return fminf(fmaxf(rintf(x / s), -qmax), qmax);   // rintf = round-half-even (matches jnp.round)
}

// ---------- fused input quant: one launch, three block ranges ----------
// blocks [0, M):                x-row quant  (qmax 127, fp32 scale, also zero s2b)
// blocks [M, M+rank):           v-row quant  (gathered; high 127 / low 7; f16 scale out)
// blocks [M+rank, M+rank+out_f): u-row gather quant (two reductions)

__global__ __launch_bounds__(256) void quant_all_kernel(
    const float* __restrict__ x, const float* __restrict__ vw,
    const float* __restrict__ uw,
    const int* __restrict__ hi, const int* __restrict__ lo,
    int M, int r_high, int rank, int C,
    char* __restrict__ xq, float* __restrict__ xs,
    char* __restrict__ vq, float* __restrict__ vs,
    char* __restrict__ uq, float* __restrict__ ush, float* __restrict__ usl,
    unsigned* __restrict__ s2b) {
  __shared__ float red[4];
  int t = threadIdx.x;
  int b = blockIdx.x;
  if (b < M) {
    int row = b;
    int z = row * 256 + t;
    if (z < 2 * M) s2b[z] = 0u;          // zero per launch (graph replays)
    const float4* src = (const float4*)(x + (size_t)row * C);
    float4 v[4];
    float m = 0.f;
#pragma unroll
    for (int i = 0; i < 4; ++i) {
      v[i] = src[t + i * 256];
      m = fmaxf(m, fmaxf(fmaxf(fabsf(v[i].x), fabsf(v[i].y)),
                         fmaxf(fabsf(v[i].z), fabsf(v[i].w))));
    }
    m = blk_absmax(m, red);
    float s = fmaxf(m, 1e-8f) / 127.0f;   // x_scale stays fp32 (no f16 round)
    if (t == 0) xs[row] = s;
    char4* dst = (char4*)(xq + (size_t)row * C);
#pragma unroll
    for (int i = 0; i < 4; ++i) {
      char4 o;
      o.x = (char)qclip(v[i].x, s, 127.f);
      o.y = (char)qclip(v[i].y, s, 127.f);
      o.z = (char)qclip(v[i].z, s, 127.f);
      o.w = (char)qclip(v[i].w, s, 127.f);
      dst[t + i * 256] = o;
    }
  } else if (b < M + rank) {
    int vb = b - M;
    int srow; float qmax;
    if (vb < r_high) { srow = hi[vb]; qmax = 127.f; }
    else             { srow = lo[vb - r_high]; qmax = 7.f; }
    const float4* src = (const float4*)(vw + (size_t)srow * C);
    float4 v[4];
    float m = 0.f;
#pragma unroll
    for (int i = 0; i < 4; ++i) {
      v[i] = src[t + i * 256];
      m = fmaxf(m, fmaxf(fmaxf(fabsf(v[i].x), fabsf(v[i].y)),
                         fmaxf(fabsf(v[i].z), fabsf(v[i].w))));
    }
    m = blk_absmax(m, red);
    float s = fmaxf(m, 1e-8f) / qmax;     // quantize with fp32 scale
    if (t == 0) vs[vb] = f16round(s);     // output-scale goes through f16
    char4* dst = (char4*)(vq + (size_t)vb * C);
#pragma unroll
    for (int i = 0; i < 4; ++i) {
      char4 o;
      o.x = (char)qclip(v[i].x, s, qmax);
      o.y = (char)qclip(v[i].y, s, qmax);
      o.z = (char)qclip(v[i].z, s, qmax);
      o.w = (char)qclip(v[i].w, s, qmax);
      dst[t + i * 256] = o;
    }
  } else {
    int i = b - M - rank;
    const float* urow = uw + (size_t)i * rank;
    // high path (r_high == 256 == blockDim)
    float hv = urow[hi[t]];
    float mh = blk_absmax(fabsf(hv), red);
    float sh = fmaxf(mh, 1e-8f) / 127.f;
    uq[(size_t)i * rank + t] = (char)qclip(hv, sh, 127.f);
    if (t == 0) ush[i] = f16round(sh);
    // low path (768 = 3*256)
    float lv[3]; float ml = 0.f;
#pragma unroll
    for (int j = 0; j < 3; ++j) {
      lv[j] = urow[lo[t + j * 256]];
      ml = fmaxf(ml, fabsf(lv[j]));
    }
    ml = blk_absmax(ml, red);
    float sl = fmaxf(ml, 1e-8f) / 7.f;
#pragma unroll
    for (int j = 0; j < 3; ++j)
      uq[(size_t)i * rank + r_high + t + j * 256] = (char)qclip(lv[j], sl, 7.f);
    if (t == 0) usl[i] = f16round(sl);
  }
}

// ---------- re-quant of y1 (lean): scales precomputed by gemm1 atomics ----------
// s2b[row] = high-half absmax bits, s2b[M+row] = low-half absmax bits.

__global__ __launch_bounds__(256) void quant_y1_kernel(
    const float4* __restrict__ y1, char4* __restrict__ y1q,
    const unsigned* __restrict__ s2b, int M) {
  int total = M * 256;                    // rank/4 = 256 float4 per row
  for (int i = blockIdx.x * 256 + threadIdx.x; i < total;
       i += gridDim.x * 256) {
    int row = i >> 8, c4 = i & 255;
    float m = __uint_as_float(s2b[(c4 < 64 ? 0 : M) + row]);
    float s = fmaxf(m, 1e-8f) / 127.f;
    float4 v = y1[i];
    char4 o;
    o.x = (char)qclip(v.x, s, 127.f);
    o.y = (char)qclip(v.y, s, 127.f);
    o.z = (char)qclip(v.z, s, 127.f);
    o.w = (char)qclip(v.w, s, 127.f);
    y1q[i] = o;
  }
}

// ---------- GEMM geometry (int8, best-known structure) ----------
// Block tile 64(M) x 128(N), BK = 128 i8 elements (128 BYTES per LDS row).
// 256 threads = 4 waves in 2x2; wave tile 32x64 = 2x4 frags of
// mfma_i32_16x16x64_i8.  Single-buffer 2-barrier K-loop.  Staging:
// global_load_lds width=16, linear LDS dest; XOR swizzle g=(l&7)^(row&7)
// pre-applied to the GLOBAL source address (rule #21).
// gemm2: NONTEMPORAL Out stores (r9 PMC: RFO fetch ~= Out size), occupancy 4.

#define BM 64
#define BN 128
#define BKT 128   // i8 elements per K-tile = bytes per LDS row

__global__ __launch_bounds__(256, 4) void gemm1_kernel(
    const char* __restrict__ A,   // xq: M x K i8
    const char* __restrict__ B,   // vq: N x K i8
    const float* __restrict__ xs, const float* __restrict__ ws,
    float* __restrict__ Y, unsigned* __restrict__ s2b,
    int M, int N, int K, int r_high) {
  __shared__ char smA[BM * BKT];   // 8 KB
  __shared__ char smB[BN * BKT];   // 16 KB
  int m0 = blockIdx.y * BM, n0 = blockIdx.x * BN;
  int tid = threadIdx.x, l = tid & 63, w = tid >> 6;
  int wr = w >> 1, wc = w & 1;

  int rb = w * 8 + (l >> 3);                // 0..31
  int g  = (l & 7) ^ (rb & 7);              // pre-swizzled 16B group
  const char* pA = A + (size_t)(m0 + rb) * K + g * 16;
  const char* pB = B + (size_t)(n0 + rb) * K + g * 16;
  char* ldsA = smA + w * 1024;              // + l*16 linear per wave
  char* ldsB = smB + w * 1024;

  i32x4 acc[2][4] = {};
  for (int k0 = 0; k0 < K; k0 += BKT) {
    __syncthreads();
#pragma unroll
    for (int i = 0; i < 2; ++i)
      GLD16(pA + (size_t)i * 32 * K + k0, ldsA + i * 4096);
#pragma unroll
    for (int i = 0; i < 4; ++i)
      GLD16(pB + (size_t)i * 32 * K + k0, ldsB + i * 4096);
    __syncthreads();
#pragma unroll
    for (int kk = 0; kk < 2; ++kk) {
      i32x4 af[2], bb[4];
      int lk = kk * 4 + (l >> 4);
#pragma unroll
      for (int f = 0; f < 2; ++f) {
        int ar = wr * 32 + f * 16 + (l & 15);
        af[f] = *(const i32x4*)(smA + ar * 128 + ((lk ^ (ar & 7)) << 4));
      }
#pragma unroll
      for (int f = 0; f < 4; ++f) {
        int br = wc * 64 + f * 16 + (l & 15);
        bb[f] = *(const i32x4*)(smB + br * 128 + ((lk ^ (br & 7)) << 4));
      }
#pragma unroll
      for (int i2 = 0; i2 < 2; ++i2)
#pragma unroll
        for (int j2 = 0; j2 < 4; ++j2)
          acc[i2][j2] = __builtin_amdgcn_mfma_i32_16x16x64_i8(
              af[i2], bb[j2], acc[i2][j2], 0, 0, 0);
    }
  }
  // epilogue: store scaled y1 + per-row partial absmax -> atomicMax (bits).
  float pm[2][4] = {};
#pragma unroll
  for (int i2 = 0; i2 < 2; ++i2)
#pragma unroll
    for (int j2 = 0; j2 < 4; ++j2) {
      int col = n0 + wc * 64 + j2 * 16 + (l & 15);
      float cs = ws[col];
#pragma unroll
      for (int r = 0; r < 4; ++r) {
        int row = m0 + wr * 32 + i2 * 16 + (l >> 4) * 4 + r;
        float v = (float)acc[i2][j2][r] * xs[row] * cs;
        Y[(size_t)row * N + col] = v;
        pm[i2][r] = fmaxf(pm[i2][r], fabsf(v));
      }
    }
#pragma unroll
  for (int i2 = 0; i2 < 2; ++i2)
#pragma unroll
    for (int r = 0; r < 4; ++r) {
#pragma unroll
      for (int off = 1; off < 16; off <<= 1)
        pm[i2][r] = fmaxf(pm[i2][r], __shfl_xor(pm[i2][r], off));
    }
  if ((l & 15) == 0) {
    unsigned* dst = s2b + (n0 < r_high ? 0 : M);   // high cols -> [0,M)
#pragma unroll
    for (int i2 = 0; i2 < 2; ++i2)
#pragma unroll
      for (int r = 0; r < 4; ++r) {
        int row = m0 + wr * 32 + i2 * 16 + (l >> 4) * 4 + r;
        atomicMax(&dst[row], __float_as_uint(pm[i2][r]));
      }
  }
}

__global__ __launch_bounds__(256, 4) void gemm2_kernel(
    const char* __restrict__ A,   // y1q: M x K i8
    const char* __restrict__ B,   // uq:  N x K i8
    const unsigned* __restrict__ s2b,
    const float* __restrict__ ush, const float* __restrict__ usl,
    const float* __restrict__ bias,
    float* __restrict__ Out, int M, int N, int K, int r_high) {
  __shared__ char smA[BM * BKT];
  __shared__ char smB[BN * BKT];
  int m0 = blockIdx.y * BM, n0 = blockIdx.x * BN;
  int tid = threadIdx.x, l = tid & 63, w = tid >> 6;
  int wr = w >> 1, wc = w & 1;

  int rb = w * 8 + (l >> 3);
  int g  = (l & 7) ^ (rb & 7);
  const char* pA = A + (size_t)(m0 + rb) * K + g * 16;
  const char* pB = B + (size_t)(n0 + rb) * K + g * 16;
  char* ldsA = smA + w * 1024;
  char* ldsB = smB + w * 1024;

  i32x4 acch[2][4] = {};
  i32x4 accl[2][4] = {};

  auto ktile = [&](int k0, i32x4(&acc)[2][4]) {
    __syncthreads();
#pragma unroll
    for (int i = 0; i < 2; ++i)
      GLD16(pA + (size_t)i * 32 * K + k0, ldsA + i * 4096);
#pragma unroll
    for (int i = 0; i < 4; ++i)
      GLD16(pB + (size_t)i * 32 * K + k0, ldsB + i * 4096);
    __syncthreads();
#pragma unroll
    for (int kk = 0; kk < 2; ++kk) {
      i32x4 af[2], bb[4];
      int lk = kk * 4 + (l >> 4);
#pragma unroll
      for (int f = 0; f < 2; ++f) {
        int ar = wr * 32 + f * 16 + (l & 15);
        af[f] = *(const i32x4*)(smA + ar * 128 + ((lk ^ (ar & 7)) << 4));
      }
#pragma unroll
      for (int f = 0; f < 4; ++f) {
        int br = wc * 64 + f * 16 + (l & 15);
        bb[f] = *(const i32x4*)(smB + br * 128 + ((lk ^ (br & 7)) << 4));
      }
#pragma unroll
      for (int i2 = 0; i2 < 2; ++i2)
#pragma unroll
        for (int j2 = 0; j2 < 4; ++j2)
          acc[i2][j2] = __builtin_amdgcn_mfma_i32_16x16x64_i8(
              af[i2], bb[j2], acc[i2][j2], 0, 0, 0);
    }
  };

  for (int k0 = 0; k0 < r_high; k0 += BKT) ktile(k0, acch);   // high
  for (int k0 = r_high; k0 < K; k0 += BKT) ktile(k0, accl);   // low

  // per-thread row scales from the atomic absmax bits (8 distinct rows)
  float sh_[2][4], sl_[2][4];
#pragma unroll
  for (int i2 = 0; i2 < 2; ++i2)
#pragma unroll
    for (int r = 0; r < 4; ++r) {
      int row = m0 + wr * 32 + i2 * 16 + (l >> 4) * 4 + r;
      sh_[i2][r] = fmaxf(__uint_as_float(s2b[row]), 1e-8f) / 127.f;
      sl_[i2][r] = fmaxf(__uint_as_float(s2b[M + row]), 1e-8f) / 127.f;
    }

#pragma unroll
  for (int i2 = 0; i2 < 2; ++i2)
#pragma unroll
    for (int j2 = 0; j2 < 4; ++j2) {
      int col = n0 + wc * 64 + j2 * 16 + (l & 15);
      float uh = ush[col], ul = usl[col];
      float bc = f16round(bias[col]);
#pragma unroll
      for (int r = 0; r < 4; ++r) {
        int row = m0 + wr * 32 + i2 * 16 + (l >> 4) * 4 + r;
        float v = (float)acch[i2][j2][r] * (sh_[i2][r] * uh) +
                  (float)accl[i2][j2][r] * (sl_[i2][r] * ul) + bc;
        // Out is never re-read: nontemporal store avoids RFO fetch.
        __builtin_nontemporal_store(v, &Out[(size_t)row * N + col]);
      }
    }
}

// ---------- launch ----------

extern "C" void kernel_launch(void* const* d_in, const int* in_sizes, int n_in,
                              void* d_out, int out_size, void* d_ws, size_t ws_size,
                              hipStream_t stream) {
  const float* x    = (const float*)d_in[0];
  const float* uw   = (const float*)d_in[1];
  const float* vw   = (const float*)d_in[2];
  const float* bias = (const float*)d_in[3];
  const int*   hi   = (const int*)d_in[4];
  const int*   lo   = (const int*)d_in[5];

  const int in_f = 4096, out_f = 4096;
  const int rank   = in_sizes[1] / out_f;     // 1024
  const int r_high = in_sizes[4];             // 256
  const int M      = in_sizes[0] / in_f;      // 8192

  char* p = (char*)d_ws;
  auto take = [&](size_t bytes) {
    char* r = p;
    p += (bytes + 255) & ~(size_t)255;
    return r;
  };
  char*     xq  = take((size_t)M * in_f);
  float*    xs  = (float*)take((size_t)M * 4);
  char*     vq  = take((size_t)rank * in_f);
  float*    vs  = (float*)take((size_t)rank * 4);
  char*     uq  = take((size_t)out_f * rank);
  float*    ush = (float*)take((size_t)out_f * 4);
  float*    usl = (float*)take((size_t)out_f * 4);
  float*    y1  = (float*)take((size_t)M * rank * 4);
  char*     y1q = take((size_t)M * rank);
  unsigned* s2b = (unsigned*)take((size_t)2 * M * 4);

  quant_all_kernel<<<M + rank + out_f, 256, 0, stream>>>(
      x, vw, uw, hi, lo, M, r_high, rank, in_f,
      xq, xs, vq, vs, uq, ush, usl, s2b);
  gemm1_kernel<<<dim3(rank / BN, M / BM), 256, 0, stream>>>(
      xq, vq, xs, vs, y1, s2b, M, rank, in_f, r_high);
  quant_y1_kernel<<<4096, 256, 0, stream>>>(
      (const float4*)y1, (char4*)y1q, s2b, M);
  gemm2_kernel<<<dim3(out_f / BN, M / BM), 256, 0, stream>>>(
      y1q, uq, s2b, ush, usl, bias, (float*)d_out, M, out_f, rank, r_high);
}